// Round 1
// baseline (1541.954 us; speedup 1.0000x reference)
//
#include <hip/hip_runtime.h>

#define N_NODES 100000
#define N_EDGES 1600000
#define DIM 64
#define NLAYERS 5
#define NUM_GRAPHS 256
#define BN_EPS 1e-5f
#define STATS_BLOCKS 256
#define CSR_CAP 64
#define OV_CAP 65536

// ---------------------------------------------------------------------------
// CSR build: cursor must be zeroed before. cursor[t] ends up = in-degree(t).
// Slots beyond CSR_CAP go to the overflow list (expected count: 0; Poisson(16)
// tail beyond 64 is ~1e-19 per node, but correctness is guaranteed anyway).
// ---------------------------------------------------------------------------
__global__ void build_csr_kernel(const int* __restrict__ ei, int* __restrict__ cursor,
                                 int* __restrict__ csr, int* __restrict__ ovcnt,
                                 int* __restrict__ ovedges) {
    int e = blockIdx.x * 256 + threadIdx.x;
    if (e >= N_EDGES) return;
    int s = ei[e];
    int t = ei[N_EDGES + e];
    int slot = atomicAdd(&cursor[t], 1);
    if (slot < CSR_CAP) {
        csr[(long)t * CSR_CAP + slot] = s;
    } else {
        int o = atomicAdd(ovcnt, 1);
        if (o < OV_CAP) ovedges[o] = e;
    }
}

// ---------------------------------------------------------------------------
// Aggregate: wave = one node, lane = one dim. Coalesced 256B row gathers,
// no atomics. agg is fully overwritten (no memset needed).
// ---------------------------------------------------------------------------
__global__ void aggregate_kernel(const int* __restrict__ csr, const int* __restrict__ deg,
                                 const float* __restrict__ h, long hstride,
                                 float* __restrict__ agg) {
    long tid = (long)blockIdx.x * 256 + threadIdx.x;
    int n = (int)(tid >> 6);
    int d = (int)(tid & 63);
    if (n >= N_NODES) return;
    int cnt = min(deg[n], CSR_CAP);
    const int* row = csr + (long)n * CSR_CAP;
    float acc = 0.f;
    for (int k = 0; k < cnt; ++k) {
        int s = row[k];  // uniform across the wave -> broadcast
        acc += h[(long)s * hstride + d];
    }
    agg[(long)n * DIM + d] = acc;
}

// Handle (expected-zero) overflow edges with f32 atomics on top of agg.
__global__ void overflow_kernel(const int* __restrict__ ovedges, const int* __restrict__ ovcnt,
                                const int* __restrict__ ei, const float* __restrict__ h,
                                long hstride, float* __restrict__ agg) {
    int cnt = *ovcnt;
    if (cnt > OV_CAP) cnt = OV_CAP;
    int w = (blockIdx.x * blockDim.x + threadIdx.x) >> 6;
    int d = threadIdx.x & 63;
    int nw = (gridDim.x * blockDim.x) >> 6;
    for (int i = w; i < cnt; i += nw) {
        int e = ovedges[i];
        int s = ei[e];
        int t = ei[N_EDGES + e];
        atomicAdd(&agg[(long)t * DIM + d], h[(long)s * hstride + d]);
    }
}

// ---------------------------------------------------------------------------
// out[n] = relu( (in[n](+agg[n])) @ W + b ).  One thread per node; 64 static
// accumulators in VGPRs; W read from LDS with uniform (broadcast) float4
// reads; activations streamed via runtime d4 loop (no runtime-indexed
// per-thread arrays -> no scratch).
// ---------------------------------------------------------------------------
__global__ __launch_bounds__(256) void mlp_gemm_kernel(
        const float* __restrict__ in, long in_stride, const float* __restrict__ agg,
        const float* __restrict__ W, const float* __restrict__ b,
        float* __restrict__ out) {
    __shared__ __align__(16) float sW[DIM * DIM];
    __shared__ float sb[DIM];
    for (int k = threadIdx.x; k < DIM * DIM / 4; k += 256)
        ((float4*)sW)[k] = ((const float4*)W)[k];
    if (threadIdx.x < DIM) sb[threadIdx.x] = b[threadIdx.x];
    __syncthreads();

    int n = blockIdx.x * 256 + threadIdx.x;
    if (n >= N_NODES) return;
    const float* inr = in + (long)n * in_stride;
    const float* ar = agg ? agg + (long)n * DIM : nullptr;

    float acc[DIM];
#pragma unroll
    for (int j = 0; j < DIM; ++j) acc[j] = sb[j];

    for (int d4 = 0; d4 < DIM / 4; ++d4) {
        float4 zv = *(const float4*)(inr + d4 * 4);
        if (ar) {
            float4 g = *(const float4*)(ar + d4 * 4);
            zv.x += g.x; zv.y += g.y; zv.z += g.z; zv.w += g.w;
        }
        const float* w0 = sW + (d4 * 4 + 0) * DIM;
        const float* w1 = sW + (d4 * 4 + 1) * DIM;
        const float* w2 = sW + (d4 * 4 + 2) * DIM;
        const float* w3 = sW + (d4 * 4 + 3) * DIM;
#pragma unroll
        for (int j = 0; j < DIM; j += 4) {
            float4 a0 = *(const float4*)(w0 + j);
            float4 a1 = *(const float4*)(w1 + j);
            float4 a2 = *(const float4*)(w2 + j);
            float4 a3 = *(const float4*)(w3 + j);
            acc[j + 0] += zv.x * a0.x + zv.y * a1.x + zv.z * a2.x + zv.w * a3.x;
            acc[j + 1] += zv.x * a0.y + zv.y * a1.y + zv.z * a2.y + zv.w * a3.y;
            acc[j + 2] += zv.x * a0.z + zv.y * a1.z + zv.z * a2.z + zv.w * a3.z;
            acc[j + 3] += zv.x * a0.w + zv.y * a1.w + zv.z * a2.w + zv.w * a3.w;
        }
    }

    float* o = out + (long)n * DIM;
#pragma unroll
    for (int k = 0; k < DIM; k += 4) {
        float4 v = { fmaxf(acc[k + 0], 0.f), fmaxf(acc[k + 1], 0.f),
                     fmaxf(acc[k + 2], 0.f), fmaxf(acc[k + 3], 0.f) };
        *(float4*)(o + k) = v;
    }
}

// ---------------------------------------------------------------------------
// BatchNorm stats: per-block partial sums (sum, sumsq) per dim, then a tiny
// finalize kernel producing per-dim scale/shift. No atomics.
// ---------------------------------------------------------------------------
__global__ void stats_partial_kernel(const float* __restrict__ z, float* __restrict__ partials) {
    __shared__ float red[2 * 256];
    int d = threadIdx.x & 63;
    int slot = threadIdx.x >> 6;
    float s1 = 0.f, s2 = 0.f;
    for (int n = blockIdx.x * 4 + slot; n < N_NODES; n += STATS_BLOCKS * 4) {
        float v = z[(long)n * DIM + d];
        s1 += v;
        s2 += v * v;
    }
    red[threadIdx.x] = s1;
    red[256 + threadIdx.x] = s2;
    __syncthreads();
    if (threadIdx.x < 64) {
        float a = red[d] + red[64 + d] + red[128 + d] + red[192 + d];
        float c = red[256 + d] + red[320 + d] + red[384 + d] + red[448 + d];
        partials[blockIdx.x * 128 + d] = a;
        partials[blockIdx.x * 128 + 64 + d] = c;
    }
}

__global__ void stats_finalize_kernel(const float* __restrict__ partials,
                                      const float* __restrict__ gamma,
                                      const float* __restrict__ beta,
                                      float* __restrict__ ss) {
    int d = threadIdx.x;
    if (d >= 64) return;
    float s1 = 0.f, s2 = 0.f;
    for (int b = 0; b < STATS_BLOCKS; ++b) {
        s1 += partials[b * 128 + d];
        s2 += partials[b * 128 + 64 + d];
    }
    float mu = s1 * (1.f / N_NODES);
    float var = s2 * (1.f / N_NODES) - mu * mu;
    float rs = 1.f / sqrtf(fmaxf(var, 0.f) + BN_EPS);
    float sc = gamma[d] * rs;
    ss[d] = sc;
    ss[64 + d] = beta[d] - mu * sc;
}

// z_bn = z*scale + shift, written into the xs output slice (row stride 320).
__global__ void bn_apply_kernel(const float* __restrict__ z, const float* __restrict__ ss,
                                float* __restrict__ outxs) {
    long t = (long)blockIdx.x * 256 + threadIdx.x;
    if (t >= (long)N_NODES * DIM) return;
    int d = (int)(t & 63);
    long n = t >> 6;
    outxs[n * (DIM * NLAYERS) + d] = z[t] * ss[d] + ss[64 + d];
}

// batch is sorted: segment starts via binary search.
__global__ void graph_starts_kernel(const int* __restrict__ batch, int* __restrict__ starts) {
    int g = threadIdx.x;
    if (g > NUM_GRAPHS) return;
    int lo = 0, hi = N_NODES;
    while (lo < hi) {
        int mid = (lo + hi) >> 1;
        if (batch[mid] < g) lo = mid + 1; else hi = mid;
    }
    starts[g] = lo;
}

__global__ void pool_kernel(const float* __restrict__ xs, const int* __restrict__ starts,
                            float* __restrict__ outpool) {
    int g = blockIdx.x;
    int d = threadIdx.x;  // 0..319
    int s = starts[g], e = starts[g + 1];
    float acc = 0.f;
    for (int n = s; n < e; ++n) acc += xs[(long)n * (DIM * NLAYERS) + d];
    outpool[(long)g * (DIM * NLAYERS) + d] = acc / fmaxf((float)(e - s), 1.f);
}

// ---------------------------------------------------------------------------
static inline size_t rup(size_t x) { return (x + 255) & ~(size_t)255; }

extern "C" void kernel_launch(void* const* d_in, const int* in_sizes, int n_in,
                              void* d_out, int out_size, void* d_ws, size_t ws_size,
                              hipStream_t stream) {
    const float* x     = (const float*)d_in[0];
    const int*   ei    = (const int*)d_in[1];
    const int*   batch = (const int*)d_in[2];
    const float* W1    = (const float*)d_in[3];
    const float* b1    = (const float*)d_in[4];
    const float* W2    = (const float*)d_in[5];
    const float* b2    = (const float*)d_in[6];
    const float* gamma = (const float*)d_in[7];
    const float* beta  = (const float*)d_in[8];

    float* out      = (float*)d_out;
    float* out_pool = out;                                     // 256 x 320
    float* out_xs   = out + (size_t)NUM_GRAPHS * DIM * NLAYERS; // 100000 x 320

    // Workspace carve-up (~78 MB total)
    char* w = (char*)d_ws;
    int*   csr      = (int*)w;    w += rup((size_t)N_NODES * CSR_CAP * 4);
    int*   cursor   = (int*)w;    w += rup((size_t)N_NODES * 4);
    int*   ovcnt    = (int*)w;    w += 256;
    int*   ovedges  = (int*)w;    w += rup((size_t)OV_CAP * 4);
    float* agg      = (float*)w;  w += rup((size_t)N_NODES * DIM * 4);
    float* bufB     = (float*)w;  w += rup((size_t)N_NODES * DIM * 4);
    float* partials = (float*)w;  w += rup((size_t)STATS_BLOCKS * 128 * 4);
    float* ss       = (float*)w;  w += 512;
    int*   starts   = (int*)w;    w += rup((size_t)(NUM_GRAPHS + 1) * 4);

    hipMemsetAsync(cursor, 0, (size_t)N_NODES * 4, stream);
    hipMemsetAsync(ovcnt, 0, 4, stream);
    build_csr_kernel<<<(N_EDGES + 255) / 256, 256, 0, stream>>>(ei, cursor, csr, ovcnt, ovedges);
    graph_starts_kernel<<<1, 320, 0, stream>>>(batch, starts);

    const float* h = x;
    long hs = DIM;
    for (int l = 0; l < NLAYERS; ++l) {
        aggregate_kernel<<<(N_NODES * DIM + 255) / 256, 256, 0, stream>>>(csr, cursor, h, hs, agg);
        overflow_kernel<<<16, 256, 0, stream>>>(ovedges, ovcnt, ei, h, hs, agg);
        // z = h + agg; bufB = relu(z @ W1 + b1)
        mlp_gemm_kernel<<<(N_NODES + 255) / 256, 256, 0, stream>>>(
            h, hs, agg, W1 + (size_t)l * DIM * DIM, b1 + (size_t)l * DIM, bufB);
        // agg (reused) = relu(bufB @ W2 + b2)
        mlp_gemm_kernel<<<(N_NODES + 255) / 256, 256, 0, stream>>>(
            bufB, DIM, nullptr, W2 + (size_t)l * DIM * DIM, b2 + (size_t)l * DIM, agg);
        stats_partial_kernel<<<STATS_BLOCKS, 256, 0, stream>>>(agg, partials);
        stats_finalize_kernel<<<1, 64, 0, stream>>>(partials, gamma + (size_t)l * DIM,
                                                    beta + (size_t)l * DIM, ss);
        bn_apply_kernel<<<((long)N_NODES * DIM + 255) / 256, 256, 0, stream>>>(
            agg, ss, out_xs + (size_t)l * DIM);
        h = out_xs + (size_t)l * DIM;
        hs = DIM * NLAYERS;
    }

    pool_kernel<<<NUM_GRAPHS, 320, 0, stream>>>(out_xs, starts, out_pool);
}

// Round 2
// 966.601 us; speedup vs baseline: 1.5952x; 1.5952x over previous
//
#include <hip/hip_runtime.h>

#define N_NODES 100000
#define N_EDGES 1600000
#define DIM 64
#define NLAYERS 5
#define NUM_GRAPHS 256
#define BN_EPS 1e-5f
#define STATS_BLOCKS 256
#define CSR_CAP 64
#define OV_CAP 65536

// ---------------------------------------------------------------------------
// CSR build: cursor must be zeroed before. cursor[t] ends up = in-degree(t).
// ---------------------------------------------------------------------------
__global__ void build_csr_kernel(const int* __restrict__ ei, int* __restrict__ cursor,
                                 int* __restrict__ csr, int* __restrict__ ovcnt,
                                 int* __restrict__ ovedges) {
    int e = blockIdx.x * 256 + threadIdx.x;
    if (e >= N_EDGES) return;
    int s = ei[e];
    int t = ei[N_EDGES + e];
    int slot = atomicAdd(&cursor[t], 1);
    if (slot < CSR_CAP) {
        csr[(long)t * CSR_CAP + slot] = s;
    } else {
        int o = atomicAdd(ovcnt, 1);
        if (o < OV_CAP) ovedges[o] = e;
    }
}

// Pad each node's slot list up to a multiple of 8 with node index 0 (valid,
// cache-hot row); padded slots are predicated off in aggregate_kernel.
__global__ void pad_csr_kernel(const int* __restrict__ cursor, int* __restrict__ csr) {
    int n = blockIdx.x * 256 + threadIdx.x;
    if (n >= N_NODES) return;
    int cnt = min(cursor[n], CSR_CAP);
    int cnt8 = (cnt + 7) & ~7;
    for (int k = cnt; k < cnt8; ++k) csr[(long)n * CSR_CAP + k] = 0;
}

// ---------------------------------------------------------------------------
// Aggregate: wave = one node, lane = one dim. Coalesced 256B row gathers,
// no atomics. 8 independent gathers in flight per wave (latency hiding);
// all predication is wave-uniform (cnt, k are uniform).
// ---------------------------------------------------------------------------
__global__ __launch_bounds__(256) void aggregate_kernel(
        const int* __restrict__ csr, const int* __restrict__ deg,
        const float* __restrict__ h, int hstride, float* __restrict__ agg) {
    long tid = (long)blockIdx.x * 256 + threadIdx.x;
    int n = (int)(tid >> 6);
    int d = (int)(tid & 63);
    if (n >= N_NODES) return;
    int cnt = min(deg[n], CSR_CAP);
    int cnt8 = (cnt + 7) & ~7;
    const int* row = csr + (long)n * CSR_CAP;
    float a0 = 0.f, a1 = 0.f, a2 = 0.f, a3 = 0.f;
    float a4 = 0.f, a5 = 0.f, a6 = 0.f, a7 = 0.f;
    for (int k = 0; k < cnt8; k += 8) {
        int s0 = row[k + 0], s1 = row[k + 1], s2 = row[k + 2], s3 = row[k + 3];
        int s4 = row[k + 4], s5 = row[k + 5], s6 = row[k + 6], s7 = row[k + 7];
        float v0 = h[(long)s0 * hstride + d];
        float v1 = h[(long)s1 * hstride + d];
        float v2 = h[(long)s2 * hstride + d];
        float v3 = h[(long)s3 * hstride + d];
        float v4 = h[(long)s4 * hstride + d];
        float v5 = h[(long)s5 * hstride + d];
        float v6 = h[(long)s6 * hstride + d];
        float v7 = h[(long)s7 * hstride + d];
        if (k + 0 < cnt) a0 += v0;
        if (k + 1 < cnt) a1 += v1;
        if (k + 2 < cnt) a2 += v2;
        if (k + 3 < cnt) a3 += v3;
        if (k + 4 < cnt) a4 += v4;
        if (k + 5 < cnt) a5 += v5;
        if (k + 6 < cnt) a6 += v6;
        if (k + 7 < cnt) a7 += v7;
    }
    agg[(long)n * DIM + d] = ((a0 + a1) + (a2 + a3)) + ((a4 + a5) + (a6 + a7));
}

// Handle (expected-zero) overflow edges with f32 atomics on top of agg.
__global__ void overflow_kernel(const int* __restrict__ ovedges, const int* __restrict__ ovcnt,
                                const int* __restrict__ ei, const float* __restrict__ h,
                                int hstride, float* __restrict__ agg) {
    int cnt = *ovcnt;
    if (cnt > OV_CAP) cnt = OV_CAP;
    int w = (blockIdx.x * blockDim.x + threadIdx.x) >> 6;
    int d = threadIdx.x & 63;
    int nw = (gridDim.x * blockDim.x) >> 6;
    for (int i = w; i < cnt; i += nw) {
        int e = ovedges[i];
        int s = ei[e];
        int t = ei[N_EDGES + e];
        atomicAdd(&agg[(long)t * DIM + d], h[(long)s * hstride + d]);
    }
}

// ---------------------------------------------------------------------------
// out[n] = relu( (in[n](+agg[n])) @ W + b ).  One thread per node; 64 static
// accumulators in VGPRs; W read from LDS with uniform (broadcast) float4
// reads; activations streamed via runtime d4 loop.
// ---------------------------------------------------------------------------
__global__ __launch_bounds__(256) void mlp_gemm_kernel(
        const float* __restrict__ in, int in_stride, const float* __restrict__ agg,
        const float* __restrict__ W, const float* __restrict__ b,
        float* __restrict__ out) {
    __shared__ __align__(16) float sW[DIM * DIM];
    __shared__ float sb[DIM];
    for (int k = threadIdx.x; k < DIM * DIM / 4; k += 256)
        ((float4*)sW)[k] = ((const float4*)W)[k];
    if (threadIdx.x < DIM) sb[threadIdx.x] = b[threadIdx.x];
    __syncthreads();

    int n = blockIdx.x * 256 + threadIdx.x;
    if (n >= N_NODES) return;
    const float* inr = in + (long)n * in_stride;
    const float* ar = agg ? agg + (long)n * DIM : nullptr;

    float acc[DIM];
#pragma unroll
    for (int j = 0; j < DIM; ++j) acc[j] = sb[j];

    for (int d4 = 0; d4 < DIM / 4; ++d4) {
        float4 zv = *(const float4*)(inr + d4 * 4);
        if (ar) {
            float4 g = *(const float4*)(ar + d4 * 4);
            zv.x += g.x; zv.y += g.y; zv.z += g.z; zv.w += g.w;
        }
        const float* w0 = sW + (d4 * 4 + 0) * DIM;
        const float* w1 = sW + (d4 * 4 + 1) * DIM;
        const float* w2 = sW + (d4 * 4 + 2) * DIM;
        const float* w3 = sW + (d4 * 4 + 3) * DIM;
#pragma unroll
        for (int j = 0; j < DIM; j += 4) {
            float4 a0 = *(const float4*)(w0 + j);
            float4 a1 = *(const float4*)(w1 + j);
            float4 a2 = *(const float4*)(w2 + j);
            float4 a3 = *(const float4*)(w3 + j);
            acc[j + 0] += zv.x * a0.x + zv.y * a1.x + zv.z * a2.x + zv.w * a3.x;
            acc[j + 1] += zv.x * a0.y + zv.y * a1.y + zv.z * a2.y + zv.w * a3.y;
            acc[j + 2] += zv.x * a0.z + zv.y * a1.z + zv.z * a2.z + zv.w * a3.z;
            acc[j + 3] += zv.x * a0.w + zv.y * a1.w + zv.z * a2.w + zv.w * a3.w;
        }
    }

    float* o = out + (long)n * DIM;
#pragma unroll
    for (int k = 0; k < DIM; k += 4) {
        float4 v = { fmaxf(acc[k + 0], 0.f), fmaxf(acc[k + 1], 0.f),
                     fmaxf(acc[k + 2], 0.f), fmaxf(acc[k + 3], 0.f) };
        *(float4*)(o + k) = v;
    }
}

// ---------------------------------------------------------------------------
// BatchNorm stats: per-block partial sums (sum, sumsq) per dim; unrolled x4
// (independent strided loads, wave-uniform guards). Then finalize.
// ---------------------------------------------------------------------------
__global__ void stats_partial_kernel(const float* __restrict__ z, float* __restrict__ partials) {
    __shared__ float red[2 * 256];
    int d = threadIdx.x & 63;
    int slot = threadIdx.x >> 6;
    const int S = STATS_BLOCKS * 4;  // 1024 row stride
    float s1 = 0.f, s2 = 0.f;
    int n = blockIdx.x * 4 + slot;
    for (; n + 3 * S < N_NODES; n += 4 * S) {
        float v0 = z[(long)(n + 0 * S) * DIM + d];
        float v1 = z[(long)(n + 1 * S) * DIM + d];
        float v2 = z[(long)(n + 2 * S) * DIM + d];
        float v3 = z[(long)(n + 3 * S) * DIM + d];
        s1 += v0 + v1 + v2 + v3;
        s2 += v0 * v0 + v1 * v1 + v2 * v2 + v3 * v3;
    }
    for (; n < N_NODES; n += S) {
        float v = z[(long)n * DIM + d];
        s1 += v;
        s2 += v * v;
    }
    red[threadIdx.x] = s1;
    red[256 + threadIdx.x] = s2;
    __syncthreads();
    if (threadIdx.x < 64) {
        float a = red[d] + red[64 + d] + red[128 + d] + red[192 + d];
        float c = red[256 + d] + red[320 + d] + red[384 + d] + red[448 + d];
        partials[blockIdx.x * 128 + d] = a;
        partials[blockIdx.x * 128 + 64 + d] = c;
    }
}

__global__ void stats_finalize_kernel(const float* __restrict__ partials,
                                      const float* __restrict__ gamma,
                                      const float* __restrict__ beta,
                                      float* __restrict__ ss) {
    int d = threadIdx.x;
    if (d >= 64) return;
    float s1 = 0.f, s2 = 0.f;
    for (int b = 0; b < STATS_BLOCKS; ++b) {
        s1 += partials[b * 128 + d];
        s2 += partials[b * 128 + 64 + d];
    }
    float mu = s1 * (1.f / N_NODES);
    float var = s2 * (1.f / N_NODES) - mu * mu;
    float rs = 1.f / sqrtf(fmaxf(var, 0.f) + BN_EPS);
    float sc = gamma[d] * rs;
    ss[d] = sc;
    ss[64 + d] = beta[d] - mu * sc;
}

// z_bn = z*scale + shift, float4-vectorized, written into xs slice (stride 320).
__global__ void bn_apply_kernel(const float* __restrict__ z, const float* __restrict__ ss,
                                float* __restrict__ outxs) {
    long t = (long)blockIdx.x * 256 + threadIdx.x;
    if (t >= (long)N_NODES * (DIM / 4)) return;
    int r = (int)(t & 15);       // which float4 within the row
    long n = t >> 4;
    float4 v = ((const float4*)(z + n * DIM))[r];
    float4 sc = ((const float4*)ss)[r];
    float4 sh = ((const float4*)(ss + DIM))[r];
    float4 o = { v.x * sc.x + sh.x, v.y * sc.y + sh.y,
                 v.z * sc.z + sh.z, v.w * sc.w + sh.w };
    ((float4*)(outxs + n * (DIM * NLAYERS)))[r] = o;
}

// batch is sorted: segment starts via binary search.
__global__ void graph_starts_kernel(const int* __restrict__ batch, int* __restrict__ starts) {
    int g = threadIdx.x;
    if (g > NUM_GRAPHS) return;
    int lo = 0, hi = N_NODES;
    while (lo < hi) {
        int mid = (lo + hi) >> 1;
        if (batch[mid] < g) lo = mid + 1; else hi = mid;
    }
    starts[g] = lo;
}

// Pool: block = graph, 320 threads = dims; unrolled x8 over nodes for MLP.
__global__ void pool_kernel(const float* __restrict__ xs, const int* __restrict__ starts,
                            float* __restrict__ outpool) {
    int g = blockIdx.x;
    int d = threadIdx.x;  // 0..319
    int s = starts[g], e = starts[g + 1];
    const int LD = DIM * NLAYERS;
    float a0 = 0.f, a1 = 0.f, a2 = 0.f, a3 = 0.f;
    float a4 = 0.f, a5 = 0.f, a6 = 0.f, a7 = 0.f;
    int n = s;
    for (; n + 8 <= e; n += 8) {
        a0 += xs[(long)(n + 0) * LD + d];
        a1 += xs[(long)(n + 1) * LD + d];
        a2 += xs[(long)(n + 2) * LD + d];
        a3 += xs[(long)(n + 3) * LD + d];
        a4 += xs[(long)(n + 4) * LD + d];
        a5 += xs[(long)(n + 5) * LD + d];
        a6 += xs[(long)(n + 6) * LD + d];
        a7 += xs[(long)(n + 7) * LD + d];
    }
    for (; n < e; ++n) a0 += xs[(long)n * LD + d];
    float acc = ((a0 + a1) + (a2 + a3)) + ((a4 + a5) + (a6 + a7));
    outpool[(long)g * LD + d] = acc / fmaxf((float)(e - s), 1.f);
}

// ---------------------------------------------------------------------------
static inline size_t rup(size_t x) { return (x + 255) & ~(size_t)255; }

extern "C" void kernel_launch(void* const* d_in, const int* in_sizes, int n_in,
                              void* d_out, int out_size, void* d_ws, size_t ws_size,
                              hipStream_t stream) {
    const float* x     = (const float*)d_in[0];
    const int*   ei    = (const int*)d_in[1];
    const int*   batch = (const int*)d_in[2];
    const float* W1    = (const float*)d_in[3];
    const float* b1    = (const float*)d_in[4];
    const float* W2    = (const float*)d_in[5];
    const float* b2    = (const float*)d_in[6];
    const float* gamma = (const float*)d_in[7];
    const float* beta  = (const float*)d_in[8];

    float* out      = (float*)d_out;
    float* out_pool = out;                                      // 256 x 320
    float* out_xs   = out + (size_t)NUM_GRAPHS * DIM * NLAYERS; // 100000 x 320

    // Workspace carve-up (~78 MB total)
    char* w = (char*)d_ws;
    int*   csr      = (int*)w;    w += rup((size_t)N_NODES * CSR_CAP * 4);
    int*   cursor   = (int*)w;    w += rup((size_t)N_NODES * 4);
    int*   ovcnt    = (int*)w;    w += 256;
    int*   ovedges  = (int*)w;    w += rup((size_t)OV_CAP * 4);
    float* agg      = (float*)w;  w += rup((size_t)N_NODES * DIM * 4);
    float* bufB     = (float*)w;  w += rup((size_t)N_NODES * DIM * 4);
    float* partials = (float*)w;  w += rup((size_t)STATS_BLOCKS * 128 * 4);
    float* ss       = (float*)w;  w += 512;
    int*   starts   = (int*)w;    w += rup((size_t)(NUM_GRAPHS + 1) * 4);

    hipMemsetAsync(cursor, 0, (size_t)N_NODES * 4, stream);
    hipMemsetAsync(ovcnt, 0, 4, stream);
    build_csr_kernel<<<(N_EDGES + 255) / 256, 256, 0, stream>>>(ei, cursor, csr, ovcnt, ovedges);
    pad_csr_kernel<<<(N_NODES + 255) / 256, 256, 0, stream>>>(cursor, csr);
    graph_starts_kernel<<<1, 320, 0, stream>>>(batch, starts);

    const float* h = x;
    int hs = DIM;
    for (int l = 0; l < NLAYERS; ++l) {
        aggregate_kernel<<<((long)N_NODES * DIM + 255) / 256, 256, 0, stream>>>(csr, cursor, h, hs, agg);
        overflow_kernel<<<16, 256, 0, stream>>>(ovedges, ovcnt, ei, h, hs, agg);
        // bufB = relu((h + agg) @ W1 + b1)
        mlp_gemm_kernel<<<(N_NODES + 255) / 256, 256, 0, stream>>>(
            h, hs, agg, W1 + (size_t)l * DIM * DIM, b1 + (size_t)l * DIM, bufB);
        // agg (reused) = relu(bufB @ W2 + b2)
        mlp_gemm_kernel<<<(N_NODES + 255) / 256, 256, 0, stream>>>(
            bufB, DIM, nullptr, W2 + (size_t)l * DIM * DIM, b2 + (size_t)l * DIM, agg);
        stats_partial_kernel<<<STATS_BLOCKS, 256, 0, stream>>>(agg, partials);
        stats_finalize_kernel<<<1, 64, 0, stream>>>(partials, gamma + (size_t)l * DIM,
                                                    beta + (size_t)l * DIM, ss);
        bn_apply_kernel<<<((long)N_NODES * (DIM / 4) + 255) / 256, 256, 0, stream>>>(
            agg, ss, out_xs + (size_t)l * DIM);
        h = out_xs + (size_t)l * DIM;
        hs = DIM * NLAYERS;
    }

    pool_kernel<<<NUM_GRAPHS, 320, 0, stream>>>(out_xs, starts, out_pool);
}